// Round 4
// baseline (351.696 us; speedup 1.0000x reference)
//
#include <hip/hip_runtime.h>

#define N_NODES  100000
#define N_EDGES  1250000
#define F_IN     128
#define F_OUT    64
#define N_GRAPHS 256
#define SCAN_BLK 1024
#define N_SBLK   ((N_NODES + SCAN_BLK - 1) / SCAN_BLK)   // 98
#define XL_LD    129   // padded: compute-phase ds_read bank = (lane+k)%32, conflict-free

// ---------------- degree count over targets (col) ----------------
__global__ __launch_bounds__(256) void deg_count_k(const int* __restrict__ col,
                                                   int* __restrict__ deg) {
    int t = blockIdx.x * blockDim.x + threadIdx.x;
    int stride = gridDim.x * blockDim.x;
    for (int e = t; e < N_EDGES; e += stride)
        atomicAdd(&deg[col[e]], 1);
}

// ---------------- dis = rsqrt(deg + 1)  (self-loop included) ----------------
__global__ __launch_bounds__(256) void dis_k(const int* __restrict__ deg,
                                             float* __restrict__ dis) {
    int i = blockIdx.x * blockDim.x + threadIdx.x;
    if (i < N_NODES) dis[i] = rsqrtf((float)deg[i] + 1.0f);
}

// ---------------- y = dis[i] * (node_feat @ W^T) ----------------
// lane = node (64-node tile in LDS, coalesced staging); wave = 16-feature slice.
// W rows are wave-uniform float4 broadcasts (L1-resident, reused by 64 lanes).
__global__ __launch_bounds__(256) void linear_k(const float* __restrict__ x,
                                                const float* __restrict__ W,
                                                const float* __restrict__ dis,
                                                float* __restrict__ y) {
    __shared__ float xL[64 * XL_LD];   // 33 KB -> 4 blocks/CU
    int tid  = threadIdx.x;
    int base = blockIdx.x * 64;
    int nmax = N_NODES - base; if (nmax > 64) nmax = 64;   // last block: 32

    // stage x tile: idx = node*32 + a ; coalesced float4 global reads
    #pragma unroll
    for (int r = 0; r < 8; ++r) {
        int idx  = tid + r * 256;
        int node = idx >> 5, a = idx & 31;
        if (node < nmax) {
            const float4 v = *(const float4*)(x + (size_t)(base + node) * F_IN + a * 4);
            float* p = &xL[node * XL_LD + a * 4];
            p[0] = v.x; p[1] = v.y; p[2] = v.z; p[3] = v.w;   // 4-way conflict, amortized
        }
    }
    __syncthreads();

    int lane = tid & 63;            // node within tile
    int f0   = (tid >> 6) * 16;     // feature slice for this wave

    if (lane < nmax) {
        float acc[16];
        #pragma unroll
        for (int f = 0; f < 16; ++f) acc[f] = 0.f;

        const float* xr = &xL[lane * XL_LD];
        #pragma unroll 2
        for (int a = 0; a < 32; ++a) {
            float x0 = xr[4 * a + 0], x1 = xr[4 * a + 1];
            float x2 = xr[4 * a + 2], x3 = xr[4 * a + 3];
            #pragma unroll
            for (int f = 0; f < 16; ++f) {
                const float4 w = *(const float4*)(W + (size_t)(f0 + f) * F_IN + 4 * a);
                acc[f] = fmaf(x0, w.x, fmaf(x1, w.y, fmaf(x2, w.z, fmaf(x3, w.w, acc[f]))));
            }
        }

        float d = dis[base + lane];
        float* yp = y + (size_t)(base + lane) * F_OUT + f0;
        #pragma unroll
        for (int fq = 0; fq < 4; ++fq) {
            float4 o;
            o.x = acc[fq * 4 + 0] * d; o.y = acc[fq * 4 + 1] * d;
            o.z = acc[fq * 4 + 2] * d; o.w = acc[fq * 4 + 3] * d;
            *(float4*)(yp + fq * 4) = o;   // 64B/lane total; L2 write-combines
        }
    }
}

// ---------------- exclusive scan of deg -> offs (3 kernels) ----------------
__global__ __launch_bounds__(SCAN_BLK) void scan1_k(const int* __restrict__ deg,
                                                    int* __restrict__ offs,
                                                    int* __restrict__ bsum) {
    __shared__ int lds[SCAN_BLK];
    int tid = threadIdx.x;
    int i = blockIdx.x * SCAN_BLK + tid;
    int v = (i < N_NODES) ? deg[i] : 0;
    lds[tid] = v;
    __syncthreads();
    for (int off = 1; off < SCAN_BLK; off <<= 1) {
        int t = (tid >= off) ? lds[tid - off] : 0;
        __syncthreads();
        lds[tid] += t;
        __syncthreads();
    }
    if (i < N_NODES) offs[i] = lds[tid] - v;      // exclusive within block
    if (tid == SCAN_BLK - 1) bsum[blockIdx.x] = lds[tid];
}

__global__ __launch_bounds__(128) void scan2_k(int* __restrict__ bsum) {
    __shared__ int lds[128];
    int tid = threadIdx.x;
    int v = (tid < N_SBLK) ? bsum[tid] : 0;
    lds[tid] = v;
    __syncthreads();
    for (int off = 1; off < 128; off <<= 1) {
        int t = (tid >= off) ? lds[tid - off] : 0;
        __syncthreads();
        lds[tid] += t;
        __syncthreads();
    }
    if (tid < N_SBLK) bsum[tid] = lds[tid] - v;   // exclusive block offsets
}

__global__ __launch_bounds__(SCAN_BLK) void scan3_k(int* __restrict__ offs,
                                                    const int* __restrict__ bsum,
                                                    int* __restrict__ cursor) {
    int i = blockIdx.x * SCAN_BLK + threadIdx.x;
    if (i < N_NODES) {
        int o = offs[i] + bsum[blockIdx.x];
        offs[i] = o;
        cursor[i] = o;
    }
}

// ---------------- fill CSR bucket: bucket[slot] = row ----------------
__global__ __launch_bounds__(256) void fill_k(const int* __restrict__ row,
                                              const int* __restrict__ col,
                                              int* __restrict__ cursor,
                                              int* __restrict__ bucket) {
    int t = blockIdx.x * blockDim.x + threadIdx.x;
    int stride = gridDim.x * blockDim.x;
    for (int e = t; e < N_EDGES; e += stride) {
        int c = col[e];
        int r = row[e];
        int p = atomicAdd(&cursor[c], 1);
        bucket[p] = r;
    }
}

// ---------------- fused gather + epilogue + mean-pool ----------------
// 4 waves/block, each wave handles 8 consecutive nodes; lane = feature.
// After fill_k, cursor[i] == offs[i] + deg[i] (bucket end).
__global__ __launch_bounds__(256) void gather_pool_k(const float* __restrict__ y,
                                                     const int* __restrict__ offs,
                                                     const int* __restrict__ cend,
                                                     const int* __restrict__ bucket,
                                                     const float* __restrict__ dis,
                                                     const int* __restrict__ batch,
                                                     const float* __restrict__ bias,
                                                     float* __restrict__ psum,
                                                     int* __restrict__ pcnt) {
    int lane = threadIdx.x & 63;
    int wid  = threadIdx.x >> 6;
    int i0   = (blockIdx.x * 4 + wid) * 8;   // 100000 = 3125 * 32, exact
    float bf = bias[lane];

    float racc = 0.f;
    int cur = -1, runlen = 0;
    for (int n = 0; n < 8; ++n) {
        int i = i0 + n;
        int s = __builtin_amdgcn_readfirstlane(offs[i]);
        int e = __builtin_amdgcn_readfirstlane(cend[i]);
        float acc = y[(size_t)i * F_OUT + lane];   // self-loop: dis[i]*y[i] term
        int j = s;
        for (; j + 3 < e; j += 4) {
            int r0 = bucket[j], r1 = bucket[j + 1];
            int r2 = bucket[j + 2], r3 = bucket[j + 3];
            float v0 = y[(size_t)r0 * F_OUT + lane];
            float v1 = y[(size_t)r1 * F_OUT + lane];
            float v2 = y[(size_t)r2 * F_OUT + lane];
            float v3 = y[(size_t)r3 * F_OUT + lane];
            acc += (v0 + v1) + (v2 + v3);
        }
        for (; j < e; ++j)
            acc += y[(size_t)bucket[j] * F_OUT + lane];

        float v = fmaxf(fmaf(dis[i], acc, bf), 0.f);
        int g = batch[i];
        if (g != cur) {
            if (cur >= 0) {
                atomicAdd(&psum[cur * F_OUT + lane], racc);
                if (lane == 0) atomicAdd(&pcnt[cur], runlen);
            }
            cur = g; racc = 0.f; runlen = 0;
        }
        racc += v; runlen++;
    }
    if (cur >= 0) {
        atomicAdd(&psum[cur * F_OUT + lane], racc);
        if (lane == 0) atomicAdd(&pcnt[cur], runlen);
    }
}

// ---------------- out = psum / max(count,1) ----------------
__global__ __launch_bounds__(256) void final_k(const float* __restrict__ psum,
                                               const int* __restrict__ pcnt,
                                               float* __restrict__ out) {
    int t = blockIdx.x * blockDim.x + threadIdx.x;
    if (t < N_GRAPHS * F_OUT) {
        int g = t >> 6;
        float c = (float)(pcnt[g] > 1 ? pcnt[g] : 1);
        out[t] = psum[t] / c;
    }
}

extern "C" void kernel_launch(void* const* d_in, const int* in_sizes, int n_in,
                              void* d_out, int out_size, void* d_ws, size_t ws_size,
                              hipStream_t stream) {
    const float* node_feat = (const float*)d_in[0];
    const int*   edges     = (const int*)d_in[1];   // [2, E] flat: row then col
    const int*   batch     = (const int*)d_in[2];
    const float* W         = (const float*)d_in[3];
    const float* b         = (const float*)d_in[4];

    // workspace carve-up (~32 MB)
    float* y      = (float*)d_ws;                        // N*64
    int*   deg    = (int*)(y + (size_t)N_NODES * F_OUT); // N
    float* psum   = (float*)(deg + N_NODES);             // G*64
    int*   pcnt   = (int*)(psum + N_GRAPHS * F_OUT);     // G
    float* dis    = (float*)(pcnt + N_GRAPHS);           // N
    int*   offs   = (int*)(dis + N_NODES);               // N
    int*   cursor = offs + N_NODES;                      // N
    int*   bsum   = cursor + N_NODES;                    // 128
    int*   bucket = bsum + 128;                          // E

    // zero deg + psum + pcnt (contiguous)
    size_t zbytes = ((size_t)N_NODES + N_GRAPHS * F_OUT + N_GRAPHS) * 4;
    hipMemsetAsync(deg, 0, zbytes, stream);

    const int* row = edges;
    const int* col = edges + N_EDGES;

    deg_count_k<<<2048, 256, 0, stream>>>(col, deg);
    dis_k<<<(N_NODES + 255) / 256, 256, 0, stream>>>(deg, dis);
    linear_k<<<(N_NODES + 63) / 64, 256, 0, stream>>>(node_feat, W, dis, y);
    scan1_k<<<N_SBLK, SCAN_BLK, 0, stream>>>(deg, offs, bsum);
    scan2_k<<<1, 128, 0, stream>>>(bsum);
    scan3_k<<<N_SBLK, SCAN_BLK, 0, stream>>>(offs, bsum, cursor);
    fill_k<<<2048, 256, 0, stream>>>(row, col, cursor, bucket);
    gather_pool_k<<<N_NODES / 32, 256, 0, stream>>>(y, offs, cursor, bucket,
                                                    dis, batch, b, psum, pcnt);
    final_k<<<(N_GRAPHS * F_OUT + 255) / 256, 256, 0, stream>>>(psum, pcnt, (float*)d_out);
}

// Round 5
// 329.015 us; speedup vs baseline: 1.0689x; 1.0689x over previous
//
#include <hip/hip_runtime.h>

#define N_NODES  100000
#define N_EDGES  1250000
#define F_IN     128
#define F_OUT    64
#define N_GRAPHS 256
#define SCAN_BLK 1024
#define N_SBLK   ((N_NODES + SCAN_BLK - 1) / SCAN_BLK)   // 98
#define XL_LD    129   // odd LD: per-lane ds_read_b128 phase banks (lane+4a+j)%32 distinct

// ---------------- degree count over targets (col) ----------------
__global__ __launch_bounds__(256) void deg_count_k(const int* __restrict__ col,
                                                   int* __restrict__ deg) {
    int t = blockIdx.x * blockDim.x + threadIdx.x;
    int stride = gridDim.x * blockDim.x;
    for (int e = t; e < N_EDGES; e += stride)
        atomicAdd(&deg[col[e]], 1);
}

// ---------------- dis = rsqrt(deg + 1)  (self-loop included) ----------------
__global__ __launch_bounds__(256) void dis_k(const int* __restrict__ deg,
                                             float* __restrict__ dis) {
    int i = blockIdx.x * blockDim.x + threadIdx.x;
    if (i < N_NODES) dis[i] = rsqrtf((float)deg[i] + 1.0f);
}

// ---------------- y = dis[i] * (node_feat @ W^T) ----------------
// BOTH operands in LDS. lane = node (64-node x tile), wave = 16-feature slice.
// x: per-lane ds_read_b128, conflict-free via LD=129. W: wave-uniform address
// -> LDS broadcast (free). Inner loop has ZERO VMEM -> VALU-bound.
__global__ __launch_bounds__(256) void linear_k(const float* __restrict__ x,
                                                const float* __restrict__ W,
                                                const float* __restrict__ dis,
                                                float* __restrict__ y) {
    __shared__ __align__(16) float xL[64 * XL_LD];      // 33.0 KB
    __shared__ __align__(16) float Wt[F_OUT * F_IN];    // 32.0 KB, row-major [f][k]
    int tid  = threadIdx.x;
    int base = blockIdx.x * 64;
    int nmax = N_NODES - base; if (nmax > 64) nmax = 64;   // last block: 32

    // stage W: 2048 float4 / 256 threads = 8 each, coalesced
    #pragma unroll
    for (int i = 0; i < 8; ++i) {
        int idx = i * 256 + tid;
        ((float4*)Wt)[idx] = ((const float4*)W)[idx];
    }
    // stage x tile: idx = node*32 + a ; coalesced float4 global reads
    #pragma unroll
    for (int r = 0; r < 8; ++r) {
        int idx  = tid + r * 256;
        int node = idx >> 5, a = idx & 31;
        if (node < nmax) {
            const float4 v = *(const float4*)(x + (size_t)(base + node) * F_IN + a * 4);
            float* p = &xL[node * XL_LD + a * 4];
            p[0] = v.x; p[1] = v.y; p[2] = v.z; p[3] = v.w;   // 4-way write conflict, amortized
        }
    }
    __syncthreads();

    int lane = tid & 63;            // node within tile
    int f0   = (tid >> 6) * 16;     // feature slice for this wave

    if (lane < nmax) {
        float acc[16];
        #pragma unroll
        for (int f = 0; f < 16; ++f) acc[f] = 0.f;

        const float* xr = &xL[lane * XL_LD];
        #pragma unroll 4
        for (int a = 0; a < 32; ++a) {
            const float4 xa = *(const float4*)(xr + 4 * a);            // b128, conflict-free
            #pragma unroll
            for (int f = 0; f < 16; ++f) {
                const float4 w = *(const float4*)(&Wt[(f0 + f) * F_IN + 4 * a]);  // broadcast
                acc[f] = fmaf(xa.x, w.x, fmaf(xa.y, w.y, fmaf(xa.z, w.z, fmaf(xa.w, w.w, acc[f]))));
            }
        }

        float d = dis[base + lane];
        float* yp = y + (size_t)(base + lane) * F_OUT + f0;
        #pragma unroll
        for (int fq = 0; fq < 4; ++fq) {
            float4 o;
            o.x = acc[fq * 4 + 0] * d; o.y = acc[fq * 4 + 1] * d;
            o.z = acc[fq * 4 + 2] * d; o.w = acc[fq * 4 + 3] * d;
            *(float4*)(yp + fq * 4) = o;
        }
    }
}

// ---------------- exclusive scan of deg -> offs (3 kernels) ----------------
__global__ __launch_bounds__(SCAN_BLK) void scan1_k(const int* __restrict__ deg,
                                                    int* __restrict__ offs,
                                                    int* __restrict__ bsum) {
    __shared__ int lds[SCAN_BLK];
    int tid = threadIdx.x;
    int i = blockIdx.x * SCAN_BLK + tid;
    int v = (i < N_NODES) ? deg[i] : 0;
    lds[tid] = v;
    __syncthreads();
    for (int off = 1; off < SCAN_BLK; off <<= 1) {
        int t = (tid >= off) ? lds[tid - off] : 0;
        __syncthreads();
        lds[tid] += t;
        __syncthreads();
    }
    if (i < N_NODES) offs[i] = lds[tid] - v;      // exclusive within block
    if (tid == SCAN_BLK - 1) bsum[blockIdx.x] = lds[tid];
}

__global__ __launch_bounds__(128) void scan2_k(int* __restrict__ bsum) {
    __shared__ int lds[128];
    int tid = threadIdx.x;
    int v = (tid < N_SBLK) ? bsum[tid] : 0;
    lds[tid] = v;
    __syncthreads();
    for (int off = 1; off < 128; off <<= 1) {
        int t = (tid >= off) ? lds[tid - off] : 0;
        __syncthreads();
        lds[tid] += t;
        __syncthreads();
    }
    if (tid < N_SBLK) bsum[tid] = lds[tid] - v;   // exclusive block offsets
}

__global__ __launch_bounds__(SCAN_BLK) void scan3_k(int* __restrict__ offs,
                                                    const int* __restrict__ bsum,
                                                    int* __restrict__ cursor) {
    int i = blockIdx.x * SCAN_BLK + threadIdx.x;
    if (i < N_NODES) {
        int o = offs[i] + bsum[blockIdx.x];
        offs[i] = o;
        cursor[i] = o;
    }
}

// ---------------- fill CSR bucket: bucket[slot] = row ----------------
__global__ __launch_bounds__(256) void fill_k(const int* __restrict__ row,
                                              const int* __restrict__ col,
                                              int* __restrict__ cursor,
                                              int* __restrict__ bucket) {
    int t = blockIdx.x * blockDim.x + threadIdx.x;
    int stride = gridDim.x * blockDim.x;
    for (int e = t; e < N_EDGES; e += stride) {
        int c = col[e];
        int r = row[e];
        int p = atomicAdd(&cursor[c], 1);
        bucket[p] = r;
    }
}

// ---------------- fused gather + epilogue + mean-pool ----------------
// 4 waves/block, each wave handles 8 consecutive nodes; lane = feature.
// After fill_k, cursor[i] == offs[i] + deg[i] (bucket end).
__global__ __launch_bounds__(256) void gather_pool_k(const float* __restrict__ y,
                                                     const int* __restrict__ offs,
                                                     const int* __restrict__ cend,
                                                     const int* __restrict__ bucket,
                                                     const float* __restrict__ dis,
                                                     const int* __restrict__ batch,
                                                     const float* __restrict__ bias,
                                                     float* __restrict__ psum,
                                                     int* __restrict__ pcnt) {
    int lane = threadIdx.x & 63;
    int wid  = threadIdx.x >> 6;
    int i0   = (blockIdx.x * 4 + wid) * 8;   // 100000 = 3125 * 32, exact
    float bf = bias[lane];

    float racc = 0.f;
    int cur = -1, runlen = 0;
    for (int n = 0; n < 8; ++n) {
        int i = i0 + n;
        int s = __builtin_amdgcn_readfirstlane(offs[i]);
        int e = __builtin_amdgcn_readfirstlane(cend[i]);
        float acc = y[(size_t)i * F_OUT + lane];   // self-loop: dis[i]*y[i] term
        int j = s;
        for (; j + 3 < e; j += 4) {
            int r0 = bucket[j], r1 = bucket[j + 1];
            int r2 = bucket[j + 2], r3 = bucket[j + 3];
            float v0 = y[(size_t)r0 * F_OUT + lane];
            float v1 = y[(size_t)r1 * F_OUT + lane];
            float v2 = y[(size_t)r2 * F_OUT + lane];
            float v3 = y[(size_t)r3 * F_OUT + lane];
            acc += (v0 + v1) + (v2 + v3);
        }
        for (; j < e; ++j)
            acc += y[(size_t)bucket[j] * F_OUT + lane];

        float v = fmaxf(fmaf(dis[i], acc, bf), 0.f);
        int g = batch[i];
        if (g != cur) {
            if (cur >= 0) {
                atomicAdd(&psum[cur * F_OUT + lane], racc);
                if (lane == 0) atomicAdd(&pcnt[cur], runlen);
            }
            cur = g; racc = 0.f; runlen = 0;
        }
        racc += v; runlen++;
    }
    if (cur >= 0) {
        atomicAdd(&psum[cur * F_OUT + lane], racc);
        if (lane == 0) atomicAdd(&pcnt[cur], runlen);
    }
}

// ---------------- out = psum / max(count,1) ----------------
__global__ __launch_bounds__(256) void final_k(const float* __restrict__ psum,
                                               const int* __restrict__ pcnt,
                                               float* __restrict__ out) {
    int t = blockIdx.x * blockDim.x + threadIdx.x;
    if (t < N_GRAPHS * F_OUT) {
        int g = t >> 6;
        float c = (float)(pcnt[g] > 1 ? pcnt[g] : 1);
        out[t] = psum[t] / c;
    }
}

extern "C" void kernel_launch(void* const* d_in, const int* in_sizes, int n_in,
                              void* d_out, int out_size, void* d_ws, size_t ws_size,
                              hipStream_t stream) {
    const float* node_feat = (const float*)d_in[0];
    const int*   edges     = (const int*)d_in[1];   // [2, E] flat: row then col
    const int*   batch     = (const int*)d_in[2];
    const float* W         = (const float*)d_in[3];
    const float* b         = (const float*)d_in[4];

    // workspace carve-up (~32 MB)
    float* y      = (float*)d_ws;                        // N*64
    int*   deg    = (int*)(y + (size_t)N_NODES * F_OUT); // N
    float* psum   = (float*)(deg + N_NODES);             // G*64
    int*   pcnt   = (int*)(psum + N_GRAPHS * F_OUT);     // G
    float* dis    = (float*)(pcnt + N_GRAPHS);           // N
    int*   offs   = (int*)(dis + N_NODES);               // N
    int*   cursor = offs + N_NODES;                      // N
    int*   bsum   = cursor + N_NODES;                    // 128
    int*   bucket = bsum + 128;                          // E

    // zero deg + psum + pcnt (contiguous)
    size_t zbytes = ((size_t)N_NODES + N_GRAPHS * F_OUT + N_GRAPHS) * 4;
    hipMemsetAsync(deg, 0, zbytes, stream);

    const int* row = edges;
    const int* col = edges + N_EDGES;

    deg_count_k<<<2048, 256, 0, stream>>>(col, deg);
    dis_k<<<(N_NODES + 255) / 256, 256, 0, stream>>>(deg, dis);
    linear_k<<<(N_NODES + 63) / 64, 256, 0, stream>>>(node_feat, W, dis, y);
    scan1_k<<<N_SBLK, SCAN_BLK, 0, stream>>>(deg, offs, bsum);
    scan2_k<<<1, 128, 0, stream>>>(bsum);
    scan3_k<<<N_SBLK, SCAN_BLK, 0, stream>>>(offs, bsum, cursor);
    fill_k<<<2048, 256, 0, stream>>>(row, col, cursor, bucket);
    gather_pool_k<<<N_NODES / 32, 256, 0, stream>>>(y, offs, cursor, bucket,
                                                    dis, batch, b, psum, pcnt);
    final_k<<<(N_GRAPHS * F_OUT + 255) / 256, 256, 0, stream>>>(psum, pcnt, (float*)d_out);
}

// Round 6
// 228.448 us; speedup vs baseline: 1.5395x; 1.4402x over previous
//
#include <hip/hip_runtime.h>

#define N_NODES  100000
#define N_EDGES  1250000
#define F_IN     128
#define F_OUT    64
#define N_GRAPHS 256
#define SCAN_BLK 1024
#define N_SBLK   98
#define NB_LIN   1563          // ceil(100000/64)
#define NB_DEG   2048
#define FILL_T   312576        // 1221 blocks * 256 threads

typedef __attribute__((ext_vector_type(8))) short short8;   // 8 bf16 (4 VGPRs)
typedef __attribute__((ext_vector_type(4))) float f32x4;

static __device__ __forceinline__ unsigned short f2bf(float f) {
    unsigned u = __builtin_bit_cast(unsigned, f);
    u += 0x7fff + ((u >> 16) & 1);            // RNE
    return (unsigned short)(u >> 16);
}
static __device__ __forceinline__ float bf2f(unsigned short h) {
    unsigned u = ((unsigned)h) << 16;
    return __builtin_bit_cast(float, u);
}

// ---------------- fused: MFMA linear (z = x@W^T, bf16) + degree count ----------------
// Blocks [0, NB_LIN): 64-node tile, 4 waves, each wave 16 nodes x 64 feats via
// 16x16x32 bf16 MFMA. Blocks [NB_LIN, NB_LIN+NB_DEG): grid-stride atomic degree count.
__global__ __launch_bounds__(256) void lin_deg_k(const float* __restrict__ x,
                                                 const float* __restrict__ W,
                                                 unsigned short* __restrict__ z,
                                                 const int* __restrict__ col,
                                                 int* __restrict__ deg) {
    if (blockIdx.x >= NB_LIN) {
        int t = (blockIdx.x - NB_LIN) * 256 + threadIdx.x;
        int stride = NB_DEG * 256;
        for (int e = t; e < N_EDGES; e += stride)
            atomicAdd(&deg[col[e]], 1);
        return;
    }

    // bf16 tiles, XOR-swizzled so MFMA fragment b128 reads are conflict-free
    __shared__ unsigned xs[64 * 64];   // 16 KB: 64 nodes x 128 k
    __shared__ unsigned ws[64 * 64];   // 16 KB: 64 feats x 128 k
    int tid  = threadIdx.x;
    int base = blockIdx.x * 64;
    int nmax = N_NODES - base; if (nmax > 64) nmax = 64;   // last block: 32

    #pragma unroll
    for (int rr = 0; rr < 8; ++rr) {
        int idx = rr * 256 + tid;          // 0..2047
        int n = idx >> 5, q = idx & 31;    // row, float4-index (k = 4q)
        int d   = (n << 6) + (q << 1);     // dword offset: n*64 + 2q
        int sdw = (n & 7) << 2;            // swizzle (bytes<<4 -> dwords<<2)
        // W tile (row = output feature)
        const float4 wv = *(const float4*)(W + (size_t)n * F_IN + q * 4);
        ws[(d ^ sdw)]     = (unsigned)f2bf(wv.x) | ((unsigned)f2bf(wv.y) << 16);
        ws[(d ^ sdw) + 1] = (unsigned)f2bf(wv.z) | ((unsigned)f2bf(wv.w) << 16);
        // x tile (row = node), zero-fill OOB
        float4 xv = make_float4(0.f, 0.f, 0.f, 0.f);
        if (n < nmax) xv = *(const float4*)(x + (size_t)(base + n) * F_IN + q * 4);
        xs[(d ^ sdw)]     = (unsigned)f2bf(xv.x) | ((unsigned)f2bf(xv.y) << 16);
        xs[(d ^ sdw) + 1] = (unsigned)f2bf(xv.z) | ((unsigned)f2bf(xv.w) << 16);
    }
    __syncthreads();

    int lane = tid & 63;
    int wv_  = tid >> 6;          // wave 0..3
    int m0   = wv_ << 4;          // node base within tile
    int lr   = lane & 15;
    int lg   = lane >> 4;         // 0..3

    f32x4 acc0 = (f32x4)(0.f), acc1 = (f32x4)(0.f);
    f32x4 acc2 = (f32x4)(0.f), acc3 = (f32x4)(0.f);

    #pragma unroll
    for (int t = 0; t < 4; ++t) {          // k-tiles of 32
        int nn = m0 + lr;
        int da = ((nn << 6) + (t << 4) + (lg << 2)) ^ ((nn & 7) << 2);
        short8 a = *(const short8*)(xs + da);
        #pragma unroll
        for (int ff = 0; ff < 4; ++ff) {   // feature tiles of 16
            int f  = (ff << 4) + lr;
            int db = ((f << 6) + (t << 4) + (lg << 2)) ^ ((f & 7) << 2);
            short8 b = *(const short8*)(ws + db);
            f32x4 c = (ff == 0) ? acc0 : (ff == 1) ? acc1 : (ff == 2) ? acc2 : acc3;
            c = __builtin_amdgcn_mfma_f32_16x16x32_bf16(a, b, c, 0, 0, 0);
            if (ff == 0) acc0 = c; else if (ff == 1) acc1 = c;
            else if (ff == 2) acc2 = c; else acc3 = c;
        }
    }

    // D layout: feat = ff*16 + (lane&15), node = m0 + (lane>>4)*4 + r
    #pragma unroll
    for (int r = 0; r < 4; ++r) {
        int node = m0 + (lg << 2) + r;
        if (node < nmax) {
            size_t o = (size_t)(base + node) * F_OUT + lr;
            z[o +  0] = f2bf(acc0[r]);
            z[o + 16] = f2bf(acc1[r]);
            z[o + 32] = f2bf(acc2[r]);
            z[o + 48] = f2bf(acc3[r]);
        }
    }
}

// ---------------- exclusive scan of deg -> offs ----------------
__global__ __launch_bounds__(SCAN_BLK) void scan1_k(const int* __restrict__ deg,
                                                    int* __restrict__ offs,
                                                    int* __restrict__ bsum) {
    __shared__ int lds[SCAN_BLK];
    int tid = threadIdx.x;
    int i = blockIdx.x * SCAN_BLK + tid;
    int v = (i < N_NODES) ? deg[i] : 0;
    lds[tid] = v;
    __syncthreads();
    for (int off = 1; off < SCAN_BLK; off <<= 1) {
        int t = (tid >= off) ? lds[tid - off] : 0;
        __syncthreads();
        lds[tid] += t;
        __syncthreads();
    }
    if (i < N_NODES) offs[i] = lds[tid] - v;
    if (tid == SCAN_BLK - 1) bsum[blockIdx.x] = lds[tid];
}

__global__ __launch_bounds__(128) void scan2_k(int* __restrict__ bsum) {
    __shared__ int lds[128];
    int tid = threadIdx.x;
    int v = (tid < N_SBLK) ? bsum[tid] : 0;
    lds[tid] = v;
    __syncthreads();
    for (int off = 1; off < 128; off <<= 1) {
        int t = (tid >= off) ? lds[tid - off] : 0;
        __syncthreads();
        lds[tid] += t;
        __syncthreads();
    }
    if (tid < N_SBLK) bsum[tid] = lds[tid] - v;
}

// scan3 + dis = rsqrt(deg+1) fused
__global__ __launch_bounds__(SCAN_BLK) void scan3_k(int* __restrict__ offs,
                                                    const int* __restrict__ bsum,
                                                    int* __restrict__ cursor,
                                                    const int* __restrict__ deg,
                                                    float* __restrict__ dis) {
    int i = blockIdx.x * SCAN_BLK + threadIdx.x;
    if (i < N_NODES) {
        int o = offs[i] + bsum[blockIdx.x];
        offs[i] = o;
        cursor[i] = o;
        dis[i] = rsqrtf((float)deg[i] + 1.0f);
    }
}

// ---------------- fill CSR bucket, 4 independent edges per thread ----------------
__global__ __launch_bounds__(256) void fill_k(const int* __restrict__ row,
                                              const int* __restrict__ col,
                                              int* __restrict__ cursor,
                                              int* __restrict__ bucket) {
    int t = blockIdx.x * 256 + threadIdx.x;
    int e0 = t, e1 = t + FILL_T, e2 = t + 2 * FILL_T, e3 = t + 3 * FILL_T;
    bool v3 = e3 < N_EDGES;
    int c0 = col[e0], r0 = row[e0];
    int c1 = col[e1], r1 = row[e1];
    int c2 = col[e2], r2 = row[e2];
    int c3 = v3 ? col[e3] : 0, r3 = v3 ? row[e3] : 0;
    int p0 = atomicAdd(&cursor[c0], 1);
    int p1 = atomicAdd(&cursor[c1], 1);
    int p2 = atomicAdd(&cursor[c2], 1);
    int p3 = v3 ? atomicAdd(&cursor[c3], 1) : 0;
    bucket[p0] = r0;
    bucket[p1] = r1;
    bucket[p2] = r2;
    if (v3) bucket[p3] = r3;
}

// ---------------- fused gather (bf16 z, dis folded) + epilogue + mean-pool ----------------
__global__ __launch_bounds__(256) void gather_pool_k(const unsigned short* __restrict__ z,
                                                     const int* __restrict__ offs,
                                                     const int* __restrict__ cend,
                                                     const int* __restrict__ bucket,
                                                     const float* __restrict__ dis,
                                                     const int* __restrict__ batch,
                                                     const float* __restrict__ bias,
                                                     float* __restrict__ psum,
                                                     int* __restrict__ pcnt) {
    int lane = threadIdx.x & 63;
    int wid  = threadIdx.x >> 6;
    int i0   = (blockIdx.x * 4 + wid) * 8;   // 100000 = 3125 * 32
    float bf = bias[lane];

    float racc = 0.f;
    int cur = -1, runlen = 0;
    for (int n = 0; n < 8; ++n) {
        int i = i0 + n;
        int s = __builtin_amdgcn_readfirstlane(offs[i]);
        int e = __builtin_amdgcn_readfirstlane(cend[i]);
        float di  = dis[i];
        float acc = di * bf2f(z[(size_t)i * F_OUT + lane]);   // self-loop term
        int j = s;
        for (; j + 3 < e; j += 4) {
            int r0 = bucket[j], r1 = bucket[j + 1];
            int r2 = bucket[j + 2], r3 = bucket[j + 3];
            float w0 = dis[r0], w1 = dis[r1], w2 = dis[r2], w3 = dis[r3];
            float v0 = bf2f(z[(size_t)r0 * F_OUT + lane]);
            float v1 = bf2f(z[(size_t)r1 * F_OUT + lane]);
            float v2 = bf2f(z[(size_t)r2 * F_OUT + lane]);
            float v3 = bf2f(z[(size_t)r3 * F_OUT + lane]);
            acc = fmaf(w0, v0, acc);
            acc = fmaf(w1, v1, acc);
            acc = fmaf(w2, v2, acc);
            acc = fmaf(w3, v3, acc);
        }
        for (; j < e; ++j) {
            int r = bucket[j];
            acc = fmaf(dis[r], bf2f(z[(size_t)r * F_OUT + lane]), acc);
        }

        float v = fmaxf(fmaf(di, acc, bf), 0.f);
        int g = batch[i];
        if (g != cur) {
            if (cur >= 0) {
                atomicAdd(&psum[cur * F_OUT + lane], racc);
                if (lane == 0) atomicAdd(&pcnt[cur], runlen);
            }
            cur = g; racc = 0.f; runlen = 0;
        }
        racc += v; runlen++;
    }
    if (cur >= 0) {
        atomicAdd(&psum[cur * F_OUT + lane], racc);
        if (lane == 0) atomicAdd(&pcnt[cur], runlen);
    }
}

// ---------------- out = psum / max(count,1) ----------------
__global__ __launch_bounds__(256) void final_k(const float* __restrict__ psum,
                                               const int* __restrict__ pcnt,
                                               float* __restrict__ out) {
    int t = blockIdx.x * blockDim.x + threadIdx.x;
    if (t < N_GRAPHS * F_OUT) {
        int g = t >> 6;
        float c = (float)(pcnt[g] > 1 ? pcnt[g] : 1);
        out[t] = psum[t] / c;
    }
}

extern "C" void kernel_launch(void* const* d_in, const int* in_sizes, int n_in,
                              void* d_out, int out_size, void* d_ws, size_t ws_size,
                              hipStream_t stream) {
    const float* node_feat = (const float*)d_in[0];
    const int*   edges     = (const int*)d_in[1];   // [2, E] flat: row then col
    const int*   batch     = (const int*)d_in[2];
    const float* W         = (const float*)d_in[3];
    const float* b         = (const float*)d_in[4];

    // workspace carve-up (~20 MB)
    unsigned short* z = (unsigned short*)d_ws;              // N*64 bf16
    int*   deg    = (int*)(z + (size_t)N_NODES * F_OUT);    // N
    float* psum   = (float*)(deg + N_NODES);                // G*64
    int*   pcnt   = (int*)(psum + N_GRAPHS * F_OUT);        // G
    float* dis    = (float*)(pcnt + N_GRAPHS);              // N
    int*   offs   = (int*)(dis + N_NODES);                  // N
    int*   cursor = offs + N_NODES;                         // N
    int*   bsum   = cursor + N_NODES;                       // 128
    int*   bucket = bsum + 128;                             // E

    // zero deg + psum + pcnt (contiguous)
    size_t zbytes = ((size_t)N_NODES + N_GRAPHS * F_OUT + N_GRAPHS) * 4;
    hipMemsetAsync(deg, 0, zbytes, stream);

    const int* row = edges;
    const int* col = edges + N_EDGES;

    lin_deg_k<<<NB_LIN + NB_DEG, 256, 0, stream>>>(node_feat, W, z, col, deg);
    scan1_k<<<N_SBLK, SCAN_BLK, 0, stream>>>(deg, offs, bsum);
    scan2_k<<<1, 128, 0, stream>>>(bsum);
    scan3_k<<<N_SBLK, SCAN_BLK, 0, stream>>>(offs, bsum, cursor, deg, dis);
    fill_k<<<(FILL_T / 256), 256, 0, stream>>>(row, col, cursor, bucket);
    gather_pool_k<<<N_NODES / 32, 256, 0, stream>>>(z, offs, cursor, bucket,
                                                    dis, batch, b, psum, pcnt);
    final_k<<<(N_GRAPHS * F_OUT + 255) / 256, 256, 0, stream>>>(psum, pcnt, (float*)d_out);
}

// Round 7
// 165.580 us; speedup vs baseline: 2.1240x; 1.3797x over previous
//
#include <hip/hip_runtime.h>

#define N_NODES  100000
#define N_EDGES  1250000
#define F_IN     128
#define F_OUT    64
#define N_GRAPHS 256
#define SCAN_BLK 1024
#define N_SBLK   98
#define NB_LIN   1563          // ceil(100000/64)
#define NB_DEG   2048
#define FILL_T   312576        // 1221 blocks * 256 threads; 4 edges/thread

typedef __attribute__((ext_vector_type(8))) short short8;   // 8 bf16 (4 VGPRs)
typedef __attribute__((ext_vector_type(4))) float f32x4;

static __device__ __forceinline__ unsigned short f2bf(float f) {
    unsigned u = __builtin_bit_cast(unsigned, f);
    u += 0x7fff + ((u >> 16) & 1);            // RNE
    return (unsigned short)(u >> 16);
}
static __device__ __forceinline__ float bf2f(unsigned short h) {
    unsigned u = ((unsigned)h) << 16;
    return __builtin_bit_cast(float, u);
}

// ---------------- fused: MFMA linear (z = x@W^T, bf16) + degree/rank count ----------------
// Blocks [0, NB_LIN): 64-node tile, 4 waves, each wave 16 nodes x 64 feats via
// 16x16x32 bf16 MFMA. Blocks [NB_LIN, ...): rank[e] = atomicAdd(&deg[col[e]],1).
// The atomic latency chain hides under the concurrent MFMA blocks.
__global__ __launch_bounds__(256) void lin_deg_k(const float* __restrict__ x,
                                                 const float* __restrict__ W,
                                                 unsigned short* __restrict__ z,
                                                 const int* __restrict__ col,
                                                 int* __restrict__ deg,
                                                 int* __restrict__ rank) {
    if (blockIdx.x >= NB_LIN) {
        int t = (blockIdx.x - NB_LIN) * 256 + threadIdx.x;
        int stride = NB_DEG * 256;
        for (int e = t; e < N_EDGES; e += stride)
            rank[e] = atomicAdd(&deg[col[e]], 1);   // store is coalesced (by e)
        return;
    }

    // bf16 tiles, XOR-swizzled so MFMA fragment b128 reads are conflict-free
    __shared__ unsigned xs[64 * 64];   // 16 KB: 64 nodes x 128 k
    __shared__ unsigned ws[64 * 64];   // 16 KB: 64 feats x 128 k
    int tid  = threadIdx.x;
    int base = blockIdx.x * 64;
    int nmax = N_NODES - base; if (nmax > 64) nmax = 64;   // last block: 32

    #pragma unroll
    for (int rr = 0; rr < 8; ++rr) {
        int idx = rr * 256 + tid;          // 0..2047
        int n = idx >> 5, q = idx & 31;    // row, float4-index (k = 4q)
        int d   = (n << 6) + (q << 1);     // dword offset: n*64 + 2q
        int sdw = (n & 7) << 2;            // swizzle (bytes<<4 -> dwords<<2)
        // W tile (row = output feature)
        const float4 wv = *(const float4*)(W + (size_t)n * F_IN + q * 4);
        ws[(d ^ sdw)]     = (unsigned)f2bf(wv.x) | ((unsigned)f2bf(wv.y) << 16);
        ws[(d ^ sdw) + 1] = (unsigned)f2bf(wv.z) | ((unsigned)f2bf(wv.w) << 16);
        // x tile (row = node), zero-fill OOB
        float4 xv = make_float4(0.f, 0.f, 0.f, 0.f);
        if (n < nmax) xv = *(const float4*)(x + (size_t)(base + n) * F_IN + q * 4);
        xs[(d ^ sdw)]     = (unsigned)f2bf(xv.x) | ((unsigned)f2bf(xv.y) << 16);
        xs[(d ^ sdw) + 1] = (unsigned)f2bf(xv.z) | ((unsigned)f2bf(xv.w) << 16);
    }
    __syncthreads();

    int lane = tid & 63;
    int wv_  = tid >> 6;          // wave 0..3
    int m0   = wv_ << 4;          // node base within tile
    int lr   = lane & 15;
    int lg   = lane >> 4;         // 0..3

    f32x4 acc0 = (f32x4)(0.f), acc1 = (f32x4)(0.f);
    f32x4 acc2 = (f32x4)(0.f), acc3 = (f32x4)(0.f);

    #pragma unroll
    for (int t = 0; t < 4; ++t) {          // k-tiles of 32
        int nn = m0 + lr;
        int da = ((nn << 6) + (t << 4) + (lg << 2)) ^ ((nn & 7) << 2);
        short8 a = *(const short8*)(xs + da);
        #pragma unroll
        for (int ff = 0; ff < 4; ++ff) {   // feature tiles of 16
            int f  = (ff << 4) + lr;
            int db = ((f << 6) + (t << 4) + (lg << 2)) ^ ((f & 7) << 2);
            short8 b = *(const short8*)(ws + db);
            f32x4 c = (ff == 0) ? acc0 : (ff == 1) ? acc1 : (ff == 2) ? acc2 : acc3;
            c = __builtin_amdgcn_mfma_f32_16x16x32_bf16(a, b, c, 0, 0, 0);
            if (ff == 0) acc0 = c; else if (ff == 1) acc1 = c;
            else if (ff == 2) acc2 = c; else acc3 = c;
        }
    }

    // D layout: feat = ff*16 + (lane&15), node = m0 + (lane>>4)*4 + r
    #pragma unroll
    for (int r = 0; r < 4; ++r) {
        int node = m0 + (lg << 2) + r;
        if (node < nmax) {
            size_t o = (size_t)(base + node) * F_OUT + lr;
            z[o +  0] = f2bf(acc0[r]);
            z[o + 16] = f2bf(acc1[r]);
            z[o + 32] = f2bf(acc2[r]);
            z[o + 48] = f2bf(acc3[r]);
        }
    }
}

// ---------------- exclusive scan of deg -> offs ----------------
__global__ __launch_bounds__(SCAN_BLK) void scan1_k(const int* __restrict__ deg,
                                                    int* __restrict__ offs,
                                                    int* __restrict__ bsum) {
    __shared__ int lds[SCAN_BLK];
    int tid = threadIdx.x;
    int i = blockIdx.x * SCAN_BLK + tid;
    int v = (i < N_NODES) ? deg[i] : 0;
    lds[tid] = v;
    __syncthreads();
    for (int off = 1; off < SCAN_BLK; off <<= 1) {
        int t = (tid >= off) ? lds[tid - off] : 0;
        __syncthreads();
        lds[tid] += t;
        __syncthreads();
    }
    if (i < N_NODES) offs[i] = lds[tid] - v;
    if (tid == SCAN_BLK - 1) bsum[blockIdx.x] = lds[tid];
}

__global__ __launch_bounds__(128) void scan2_k(int* __restrict__ bsum) {
    __shared__ int lds[128];
    int tid = threadIdx.x;
    int v = (tid < N_SBLK) ? bsum[tid] : 0;
    lds[tid] = v;
    __syncthreads();
    for (int off = 1; off < 128; off <<= 1) {
        int t = (tid >= off) ? lds[tid - off] : 0;
        __syncthreads();
        lds[tid] += t;
        __syncthreads();
    }
    if (tid < N_SBLK) bsum[tid] = lds[tid] - v;
}

// scan3 + dis = rsqrt(deg+1) fused
__global__ __launch_bounds__(SCAN_BLK) void scan3_k(int* __restrict__ offs,
                                                    const int* __restrict__ bsum,
                                                    const int* __restrict__ deg,
                                                    float* __restrict__ dis) {
    int i = blockIdx.x * SCAN_BLK + threadIdx.x;
    if (i < N_NODES) {
        offs[i] = offs[i] + bsum[blockIdx.x];
        dis[i] = rsqrtf((float)deg[i] + 1.0f);
    }
}

// ---------------- fill CSR bucket, atomic-free: slot = offs[col] + rank ----------------
__global__ __launch_bounds__(256) void fill_k(const int* __restrict__ row,
                                              const int* __restrict__ col,
                                              const int* __restrict__ offs,
                                              const int* __restrict__ rank,
                                              int* __restrict__ bucket) {
    int t = blockIdx.x * 256 + threadIdx.x;
    #pragma unroll
    for (int u = 0; u < 4; ++u) {
        int e = t + u * FILL_T;
        if (e < N_EDGES) {
            int c = col[e];                       // coalesced
            bucket[offs[c] + rank[e]] = row[e];   // L2 gather + scattered store
        }
    }
}

// ---------------- fused gather (bf16 z, dis folded) + epilogue + mean-pool ----------------
__global__ __launch_bounds__(256) void gather_pool_k(const unsigned short* __restrict__ z,
                                                     const int* __restrict__ offs,
                                                     const int* __restrict__ deg,
                                                     const int* __restrict__ bucket,
                                                     const float* __restrict__ dis,
                                                     const int* __restrict__ batch,
                                                     const float* __restrict__ bias,
                                                     float* __restrict__ psum,
                                                     int* __restrict__ pcnt) {
    int lane = threadIdx.x & 63;
    int wid  = threadIdx.x >> 6;
    int i0   = (blockIdx.x * 4 + wid) * 8;   // 100000 = 3125 * 32
    float bf = bias[lane];

    float racc = 0.f;
    int cur = -1, runlen = 0;
    for (int n = 0; n < 8; ++n) {
        int i = i0 + n;
        int s = __builtin_amdgcn_readfirstlane(offs[i]);
        int e = s + __builtin_amdgcn_readfirstlane(deg[i]);
        float di  = dis[i];
        float acc = di * bf2f(z[(size_t)i * F_OUT + lane]);   // self-loop term
        int j = s;
        for (; j + 3 < e; j += 4) {
            int r0 = bucket[j], r1 = bucket[j + 1];
            int r2 = bucket[j + 2], r3 = bucket[j + 3];
            float w0 = dis[r0], w1 = dis[r1], w2 = dis[r2], w3 = dis[r3];
            float v0 = bf2f(z[(size_t)r0 * F_OUT + lane]);
            float v1 = bf2f(z[(size_t)r1 * F_OUT + lane]);
            float v2 = bf2f(z[(size_t)r2 * F_OUT + lane]);
            float v3 = bf2f(z[(size_t)r3 * F_OUT + lane]);
            acc = fmaf(w0, v0, acc);
            acc = fmaf(w1, v1, acc);
            acc = fmaf(w2, v2, acc);
            acc = fmaf(w3, v3, acc);
        }
        for (; j < e; ++j) {
            int r = bucket[j];
            acc = fmaf(dis[r], bf2f(z[(size_t)r * F_OUT + lane]), acc);
        }

        float v = fmaxf(fmaf(di, acc, bf), 0.f);
        int g = batch[i];
        if (g != cur) {
            if (cur >= 0) {
                atomicAdd(&psum[cur * F_OUT + lane], racc);
                if (lane == 0) atomicAdd(&pcnt[cur], runlen);
            }
            cur = g; racc = 0.f; runlen = 0;
        }
        racc += v; runlen++;
    }
    if (cur >= 0) {
        atomicAdd(&psum[cur * F_OUT + lane], racc);
        if (lane == 0) atomicAdd(&pcnt[cur], runlen);
    }
}

// ---------------- out = psum / max(count,1) ----------------
__global__ __launch_bounds__(256) void final_k(const float* __restrict__ psum,
                                               const int* __restrict__ pcnt,
                                               float* __restrict__ out) {
    int t = blockIdx.x * blockDim.x + threadIdx.x;
    if (t < N_GRAPHS * F_OUT) {
        int g = t >> 6;
        float c = (float)(pcnt[g] > 1 ? pcnt[g] : 1);
        out[t] = psum[t] / c;
    }
}

extern "C" void kernel_launch(void* const* d_in, const int* in_sizes, int n_in,
                              void* d_out, int out_size, void* d_ws, size_t ws_size,
                              hipStream_t stream) {
    const float* node_feat = (const float*)d_in[0];
    const int*   edges     = (const int*)d_in[1];   // [2, E] flat: row then col
    const int*   batch     = (const int*)d_in[2];
    const float* W         = (const float*)d_in[3];
    const float* b         = (const float*)d_in[4];

    // workspace carve-up (~25 MB)
    unsigned short* z = (unsigned short*)d_ws;              // N*64 bf16
    int*   deg    = (int*)(z + (size_t)N_NODES * F_OUT);    // N
    float* psum   = (float*)(deg + N_NODES);                // G*64
    int*   pcnt   = (int*)(psum + N_GRAPHS * F_OUT);        // G
    float* dis    = (float*)(pcnt + N_GRAPHS);              // N
    int*   offs   = (int*)(dis + N_NODES);                  // N
    int*   bsum   = offs + N_NODES;                         // 128
    int*   bucket = bsum + 128;                             // E
    int*   rank   = bucket + N_EDGES;                       // E

    // zero deg + psum + pcnt (contiguous)
    size_t zbytes = ((size_t)N_NODES + N_GRAPHS * F_OUT + N_GRAPHS) * 4;
    hipMemsetAsync(deg, 0, zbytes, stream);

    const int* row = edges;
    const int* col = edges + N_EDGES;

    lin_deg_k<<<NB_LIN + NB_DEG, 256, 0, stream>>>(node_feat, W, z, col, deg, rank);
    scan1_k<<<N_SBLK, SCAN_BLK, 0, stream>>>(deg, offs, bsum);
    scan2_k<<<1, 128, 0, stream>>>(bsum);
    scan3_k<<<N_SBLK, SCAN_BLK, 0, stream>>>(offs, bsum, deg, dis);
    fill_k<<<(FILL_T / 256), 256, 0, stream>>>(row, col, offs, rank, bucket);
    gather_pool_k<<<N_NODES / 32, 256, 0, stream>>>(z, offs, deg, bucket,
                                                    dis, batch, b, psum, pcnt);
    final_k<<<(N_GRAPHS * F_OUT + 255) / 256, 256, 0, stream>>>(psum, pcnt, (float*)d_out);
}